// Round 1
// baseline (655.846 us; speedup 1.0000x reference)
//
#include <hip/hip_runtime.h>
#include <hip/hip_fp16.h>

#define RES 512
#define CF 32
#define PLANE_ELEMS (RES * RES)          // 262144 per channel-plane

// ---------------------------------------------------------------------------
// Pass 1: transpose C_mat [3][32][512][512] fp32 -> ws [3][512][512][32] fp16
// One thread per (p, y, x). Reads are coalesced per-c (lane stride 4B);
// writes are 64B contiguous per lane.
// ---------------------------------------------------------------------------
__global__ __launch_bounds__(256) void triplane_transpose(
    const float* __restrict__ C_mat, __half* __restrict__ ws) {
    int gid = blockIdx.x * 256 + threadIdx.x;      // (p*512 + y)*512 + x
    int x  = gid & (RES - 1);
    int py = gid >> 9;                              // p*512 + y
    int p  = py >> 9;
    int y  = py & (RES - 1);
    const float* src = C_mat + (size_t)p * CF * PLANE_ELEMS + (size_t)y * RES + x;

    __half tmp[CF];
#pragma unroll
    for (int c = 0; c < CF; ++c) {
        tmp[c] = __float2half(src[(size_t)c * PLANE_ELEMS]);
    }
    float4* dst = (float4*)(ws + (size_t)gid * CF);
    const float4* t4 = (const float4*)tmp;
#pragma unroll
    for (int k = 0; k < 4; ++k) dst[k] = t4[k];
}

// ---------------------------------------------------------------------------
// Pass 2: sample. 4 lanes per point; lane `sub` owns channels [sub*8, sub*8+8).
// Each corner fetch = one float4 (8 fp16) contiguous load; the 4 lanes of a
// point together cover the full 64B texel record.
// ---------------------------------------------------------------------------
__global__ __launch_bounds__(256) void triplane_sample(
    const float* __restrict__ xin, const __half* __restrict__ planes,
    float* __restrict__ out, int n_pts) {
    int gid = blockIdx.x * 256 + threadIdx.x;
    int n   = gid >> 2;
    int sub = gid & 3;
    if (n >= n_pts) return;

    float c0 = xin[3 * n + 0];
    float c1 = xin[3 * n + 1];
    float c2 = xin[3 * n + 2];
    float coord[3] = {c0, c1, c2};
    const int ii[3] = {0, 0, 1};
    const int jj[3] = {1, 2, 2};

    float acc[8];
#pragma unroll
    for (int k = 0; k < 8; ++k) acc[k] = 0.0f;

#pragma unroll
    for (int p = 0; p < 3; ++p) {
        float gx = coord[ii[p]];
        float gy = coord[jj[p]];
        // exact reference formula, fp32
        float ix = ((gx + 1.0f) * (float)RES - 1.0f) * 0.5f;
        float iy = ((gy + 1.0f) * (float)RES - 1.0f) * 0.5f;
        float x0f = floorf(ix), y0f = floorf(iy);
        float wx1 = ix - x0f,  wy1 = iy - y0f;
        float wx0 = 1.0f - wx1, wy0 = 1.0f - wy1;
        int x0 = (int)x0f, y0 = (int)y0f;
        int x1 = x0 + 1,   y1 = y0 + 1;

        const __half* pbase = planes + (size_t)p * PLANE_ELEMS * CF + (size_t)sub * 8;

        // corner loop: (x0,y0) (x1,y0) (x0,y1) (x1,y1)
        int   cxs[4] = {x0, x1, x0, x1};
        int   cys[4] = {y0, y0, y1, y1};
        float cws[4] = {wx0 * wy0, wx1 * wy0, wx0 * wy1, wx1 * wy1};
#pragma unroll
        for (int c = 0; c < 4; ++c) {
            int xi = cxs[c], yi = cys[c];
            bool valid = (xi >= 0) & (xi <= RES - 1) & (yi >= 0) & (yi <= RES - 1);
            int xc = min(max(xi, 0), RES - 1);
            int yc = min(max(yi, 0), RES - 1);
            float w = valid ? cws[c] : 0.0f;
            float4 raw = *(const float4*)(pbase + ((size_t)yc * RES + xc) * CF);
            const __half2* h2 = (const __half2*)&raw;
#pragma unroll
            for (int k = 0; k < 4; ++k) {
                float2 f = __half22float2(h2[k]);
                acc[2 * k + 0] += w * f.x;
                acc[2 * k + 1] += w * f.y;
            }
        }
    }

    float4* o = (float4*)(out + (size_t)n * CF + (size_t)sub * 8);
    o[0] = make_float4(acc[0], acc[1], acc[2], acc[3]);
    o[1] = make_float4(acc[4], acc[5], acc[6], acc[7]);
}

// ---------------------------------------------------------------------------
// Fallback: direct fp32 gather from native [3][32][512][512] layout
// (only used if ws_size is too small for the transposed planes).
// ---------------------------------------------------------------------------
__global__ __launch_bounds__(256) void triplane_sample_direct(
    const float* __restrict__ xin, const float* __restrict__ C_mat,
    float* __restrict__ out, int n_pts) {
    int gid = blockIdx.x * 256 + threadIdx.x;
    int n   = gid >> 2;
    int sub = gid & 3;
    if (n >= n_pts) return;

    float coord[3] = {xin[3 * n], xin[3 * n + 1], xin[3 * n + 2]};
    const int ii[3] = {0, 0, 1};
    const int jj[3] = {1, 2, 2};

    float acc[8];
#pragma unroll
    for (int k = 0; k < 8; ++k) acc[k] = 0.0f;

    for (int p = 0; p < 3; ++p) {
        float gx = coord[ii[p]];
        float gy = coord[jj[p]];
        float ix = ((gx + 1.0f) * (float)RES - 1.0f) * 0.5f;
        float iy = ((gy + 1.0f) * (float)RES - 1.0f) * 0.5f;
        float x0f = floorf(ix), y0f = floorf(iy);
        float wx1 = ix - x0f,  wy1 = iy - y0f;
        float wx0 = 1.0f - wx1, wy0 = 1.0f - wy1;
        int x0 = (int)x0f, y0 = (int)y0f;
        int x1 = x0 + 1,   y1 = y0 + 1;

        int   cxs[4] = {x0, x1, x0, x1};
        int   cys[4] = {y0, y0, y1, y1};
        float cws[4] = {wx0 * wy0, wx1 * wy0, wx0 * wy1, wx1 * wy1};
        for (int c = 0; c < 4; ++c) {
            int xi = cxs[c], yi = cys[c];
            bool valid = (xi >= 0) & (xi <= RES - 1) & (yi >= 0) & (yi <= RES - 1);
            int xc = min(max(xi, 0), RES - 1);
            int yc = min(max(yi, 0), RES - 1);
            float w = valid ? cws[c] : 0.0f;
            size_t texel = (size_t)yc * RES + xc;
#pragma unroll
            for (int k = 0; k < 8; ++k) {
                float v = C_mat[((size_t)p * CF + sub * 8 + k) * PLANE_ELEMS + texel];
                acc[k] += w * v;
            }
        }
    }

    float4* o = (float4*)(out + (size_t)n * CF + (size_t)sub * 8);
    o[0] = make_float4(acc[0], acc[1], acc[2], acc[3]);
    o[1] = make_float4(acc[4], acc[5], acc[6], acc[7]);
}

extern "C" void kernel_launch(void* const* d_in, const int* in_sizes, int n_in,
                              void* d_out, int out_size, void* d_ws, size_t ws_size,
                              hipStream_t stream) {
    const float* x     = (const float*)d_in[0];
    const float* C_mat = (const float*)d_in[1];
    float* out = (float*)d_out;
    int n_pts = in_sizes[0] / 3;

    size_t need = (size_t)3 * PLANE_ELEMS * CF * sizeof(__half);  // ~50.3 MB
    int sample_blocks = (n_pts * 4 + 255) / 256;

    if (ws_size >= need) {
        __half* planes = (__half*)d_ws;
        int tblocks = (3 * PLANE_ELEMS) / 256;  // 3072
        triplane_transpose<<<tblocks, 256, 0, stream>>>(C_mat, planes);
        triplane_sample<<<sample_blocks, 256, 0, stream>>>(x, planes, out, n_pts);
    } else {
        triplane_sample_direct<<<sample_blocks, 256, 0, stream>>>(x, C_mat, out, n_pts);
    }
}